// Round 1
// baseline (321.352 us; speedup 1.0000x reference)
//
#include <hip/hip_runtime.h>

typedef __bf16 bf16_t;
typedef __bf16 bf16x8 __attribute__((ext_vector_type(8)));
typedef float f32x4 __attribute__((ext_vector_type(4)));

static constexpr int Bq = 4, Gg = 8, Nn = 128, Tt = 6000, Hh = 384;
static constexpr int TB = 16;             // t-values per K1 block
static constexpr int MR = TB * Gg;        // 128 rows per block (row = tl*8 + g)
static constexpr int LDA = 136;           // As row stride (bf16), 272B = 68 words % 32 = 4
static constexpr int LDG = 392;           // Gi row stride (bf16), 784B = 196 words % 32 = 4
static constexpr int LDSM = 392;          // Sm/Mm row stride

// workspace layout (bytes)
static constexpr size_t OFF_WI  = 0;                                  // 384x128 bf16
static constexpr size_t OFF_WM  = OFF_WI + (size_t)Hh * Nn * 2;       // 384x384 bf16
static constexpr size_t OFF_WO  = OFF_WM + (size_t)Hh * Hh * 2;       // 128x768 bf16
static constexpr size_t OFF_ST  = OFF_WO + (size_t)Nn * 2 * Hh * 2;   // 64x2 f32 (sum,sumsq)
static constexpr size_t OFF_MRS = OFF_ST + 64 * 2 * 4;                // 64x2 f32 (mean,rstd)
static constexpr size_t OFF_GO  = (size_t)1 << 20;                    // B*T*G*N bf16
static constexpr size_t WS_NEED = OFF_GO + (size_t)Bq * Tt * Gg * Nn * 2;

// k1 dynamic-LDS offsets (bytes)
static constexpr int SM_SM = 0;        // Sm [16][392] bf16 (reuses As region)
static constexpr int SM_MM = 12544;    // Mm [16][392] bf16
static constexpr int SM_VV = 25088;    // Vv [16][128] f32
static constexpr int SM_GI = 34816;    // Gi [128][392] bf16
static constexpr int SM_STT = 135168;  // st [16] f32
static constexpr int SMEM_BYTES = 135232;
// As [128][136] bf16 lives at offset 0 (dead after GEMM1; Sm/Mm/Vv reuse it)

#define MFMA16(a, b, c) __builtin_amdgcn_mfma_f32_16x16x32_bf16((a), (b), (c), 0, 0, 0)

__global__ void k0_prep(const float* __restrict__ Wi, const float* __restrict__ Wm,
                        const float* __restrict__ Wo,
                        bf16_t* __restrict__ WiB, bf16_t* __restrict__ WmB,
                        bf16_t* __restrict__ WoB, float* __restrict__ stats) {
    int i = blockIdx.x * blockDim.x + threadIdx.x;
    const int n1 = Hh * Nn, n2 = Hh * Hh, n3 = Nn * 2 * Hh;
    for (int idx = i; idx < n1 + n2 + n3; idx += gridDim.x * blockDim.x) {
        if (idx < n1)            WiB[idx] = (bf16_t)Wi[idx];
        else if (idx < n1 + n2)  WmB[idx - n1] = (bf16_t)Wm[idx - n1];
        else                     WoB[idx - n1 - n2] = (bf16_t)Wo[idx - n1 - n2];
    }
    if (i < 128) stats[i] = 0.f;  // zero every launch: K1 atomically accumulates
}

__global__ __launch_bounds__(512, 1)
void k1_fused(const float* __restrict__ x,
              const bf16_t* __restrict__ WiB, const float* __restrict__ bi, const float* __restrict__ aip,
              const bf16_t* __restrict__ WmB, const float* __restrict__ bm, const float* __restrict__ amp,
              const bf16_t* __restrict__ WoB, const float* __restrict__ bo, const float* __restrict__ aop,
              bf16_t* __restrict__ go, float* __restrict__ stats) {
    extern __shared__ char smem[];
    bf16_t* As = (bf16_t*)(smem);
    bf16_t* Sm = (bf16_t*)(smem + SM_SM);
    bf16_t* Mm = (bf16_t*)(smem + SM_MM);
    float*  Vv = (float*)(smem + SM_VV);
    bf16_t* Gi = (bf16_t*)(smem + SM_GI);
    float*  st = (float*)(smem + SM_STT);

    const int tid  = threadIdx.x;
    const int lane = tid & 63;
    const int w    = tid >> 6;       // wave 0..7
    const int l15  = lane & 15;
    const int l4   = lane >> 4;      // 0..3
    const int b    = blockIdx.x / (Tt / TB);
    const int t0   = (blockIdx.x % (Tt / TB)) * TB;

    if (tid < 16) st[tid] = 0.f;

    // ---- stage x[b, g, n, t0:t0+16] -> As[tl*8+g][n] (bf16)
    for (int idx = tid; idx < MR * Nn; idx += 512) {
        int tl = idx & 15;
        int gn = idx >> 4;
        int g = gn >> 7;
        int n = gn & 127;
        float v = x[((size_t)((b * Gg + g) * Nn + n)) * Tt + t0 + tl];
        As[(tl * Gg + g) * LDA + n] = (bf16_t)v;
    }
    __syncthreads();

    const float ai = aip[0], am = amp[0], ao = aop[0];

    // ---- GEMM1: Gi[128][384] = prelu(As @ WiB^T + bi), K=128
    {
        const int mblk = (w >> 1) * 32;
        const int nblk = (w & 1) * 192;
        f32x4 acc[2][12];
        #pragma unroll
        for (int mi = 0; mi < 2; mi++)
            #pragma unroll
            for (int ni = 0; ni < 12; ni++) acc[mi][ni] = f32x4{0.f, 0.f, 0.f, 0.f};
        #pragma unroll
        for (int kk = 0; kk < 4; kk++) {
            const int k0 = kk * 32 + l4 * 8;
            bf16x8 a0 = *(const bf16x8*)&As[(mblk + l15) * LDA + k0];
            bf16x8 a1 = *(const bf16x8*)&As[(mblk + 16 + l15) * LDA + k0];
            #pragma unroll
            for (int ni = 0; ni < 12; ni++) {
                int col = nblk + ni * 16 + l15;
                bf16x8 bf = *(const bf16x8*)&WiB[col * Nn + k0];
                acc[0][ni] = MFMA16(a0, bf, acc[0][ni]);
                acc[1][ni] = MFMA16(a1, bf, acc[1][ni]);
            }
        }
        #pragma unroll
        for (int ni = 0; ni < 12; ni++) {
            int col = nblk + ni * 16 + l15;
            float bv = bi[col];
            #pragma unroll
            for (int mi = 0; mi < 2; mi++) {
                #pragma unroll
                for (int j = 0; j < 4; j++) {
                    int row = mblk + mi * 16 + l4 * 4 + j;
                    float v = acc[mi][ni][j] + bv;
                    v = v >= 0.f ? v : ai * v;
                    Gi[row * LDG + col] = (bf16_t)v;
                }
            }
        }
    }
    __syncthreads();

    // ---- group mean: Sm[tl][h] = (1/8) sum_g Gi[tl*8+g][h]
    for (int idx = tid; idx < TB * Hh; idx += 512) {
        int tl = idx / Hh;
        int h = idx - tl * Hh;
        float s = 0.f;
        #pragma unroll
        for (int g = 0; g < 8; g++) s += (float)Gi[(tl * 8 + g) * LDG + h];
        Sm[tl * LDSM + h] = (bf16_t)(0.125f * s);
    }
    __syncthreads();

    // ---- GEMM2: Mm[16][384] = prelu(Sm @ WmB^T + bm), K=384
    {
        const int nblk = w * 48;
        f32x4 acc2[3];
        #pragma unroll
        for (int ni = 0; ni < 3; ni++) acc2[ni] = f32x4{0.f, 0.f, 0.f, 0.f};
        #pragma unroll
        for (int kk = 0; kk < 12; kk++) {
            const int k0 = kk * 32 + l4 * 8;
            bf16x8 a = *(const bf16x8*)&Sm[l15 * LDSM + k0];
            #pragma unroll
            for (int ni = 0; ni < 3; ni++) {
                int col = nblk + ni * 16 + l15;
                bf16x8 bf = *(const bf16x8*)&WmB[col * Hh + k0];
                acc2[ni] = MFMA16(a, bf, acc2[ni]);
            }
        }
        #pragma unroll
        for (int ni = 0; ni < 3; ni++) {
            int col = nblk + ni * 16 + l15;
            float bv = bm[col];
            #pragma unroll
            for (int j = 0; j < 4; j++) {
                float v = acc2[ni][j] + bv;
                v = v >= 0.f ? v : am * v;
                Mm[(l4 * 4 + j) * LDSM + col] = (bf16_t)v;
            }
        }
    }
    __syncthreads();

    // ---- GEMM3: Vv[16][128] = Mm @ Wo2^T  (Wo2[n][o] = WoB[n*768 + 384 + o]), K=384
    {
        const int nblk = w * 16;
        f32x4 acc3 = f32x4{0.f, 0.f, 0.f, 0.f};
        #pragma unroll
        for (int kk = 0; kk < 12; kk++) {
            const int k0 = kk * 32 + l4 * 8;
            bf16x8 a = *(const bf16x8*)&Mm[l15 * LDSM + k0];
            bf16x8 bf = *(const bf16x8*)&WoB[(nblk + l15) * 768 + 384 + k0];
            acc3 = MFMA16(a, bf, acc3);
        }
        #pragma unroll
        for (int j = 0; j < 4; j++) Vv[(l4 * 4 + j) * Nn + nblk + l15] = acc3[j];
    }
    __syncthreads();

    // ---- GEMM4: go[128][128] = prelu(Gi @ Wo1^T + Vv + bo), K=384; plus LN partial stats
    {
        const int mblk = (w >> 1) * 32;
        const int nblk = (w & 1) * 64;
        f32x4 acc4[2][4];
        #pragma unroll
        for (int mi = 0; mi < 2; mi++)
            #pragma unroll
            for (int ni = 0; ni < 4; ni++) acc4[mi][ni] = f32x4{0.f, 0.f, 0.f, 0.f};
        #pragma unroll
        for (int kk = 0; kk < 12; kk++) {
            const int k0 = kk * 32 + l4 * 8;
            bf16x8 a0 = *(const bf16x8*)&Gi[(mblk + l15) * LDG + k0];
            bf16x8 a1 = *(const bf16x8*)&Gi[(mblk + 16 + l15) * LDG + k0];
            #pragma unroll
            for (int ni = 0; ni < 4; ni++) {
                int col = nblk + ni * 16 + l15;
                bf16x8 bf = *(const bf16x8*)&WoB[col * 768 + k0];
                acc4[0][ni] = MFMA16(a0, bf, acc4[0][ni]);
                acc4[1][ni] = MFMA16(a1, bf, acc4[1][ni]);
            }
        }
        // epilogue + per-(b,g) partial sums.  row = mblk+mi*16+l4*4+j  ->  g = (l4*4+j)&7
        float gsum[4] = {0.f, 0.f, 0.f, 0.f};
        float gss[4]  = {0.f, 0.f, 0.f, 0.f};
        #pragma unroll
        for (int ni = 0; ni < 4; ni++) {
            int col = nblk + ni * 16 + l15;
            float bv = bo[col];
            #pragma unroll
            for (int mi = 0; mi < 2; mi++) {
                #pragma unroll
                for (int j = 0; j < 4; j++) {
                    int row = mblk + mi * 16 + l4 * 4 + j;
                    int tl = row >> 3;
                    int g = row & 7;
                    float v = acc4[mi][ni][j] + Vv[tl * Nn + col] + bv;
                    v = v >= 0.f ? v : ao * v;
                    go[((size_t)((b * Tt + t0 + tl) * Gg + g)) * Nn + col] = (bf16_t)v;
                    gsum[j] += v;
                    gss[j] += v * v;
                }
            }
        }
        #pragma unroll
        for (int j = 0; j < 4; j++) {
            float s = gsum[j], q = gss[j];
            #pragma unroll
            for (int off = 1; off < 16; off <<= 1) {
                s += __shfl_xor(s, off, 64);
                q += __shfl_xor(q, off, 64);
            }
            if (l15 == 0) {
                int g = (l4 * 4 + j) & 7;
                atomicAdd(&st[g * 2 + 0], s);
                atomicAdd(&st[g * 2 + 1], q);
            }
        }
    }
    __syncthreads();
    if (tid < 16) atomicAdd(&stats[b * 16 + tid], st[tid]);
}

__global__ void k_final(const float* __restrict__ stats, float* __restrict__ mr) {
    int i = threadIdx.x;
    if (i < 64) {
        const float cnt = (float)Nn * (float)Tt;  // 768000 per (b,g)
        float mean = stats[i * 2] / cnt;
        float var = stats[i * 2 + 1] / cnt - mean * mean;
        mr[i * 2] = mean;
        mr[i * 2 + 1] = rsqrtf(var + 1e-8f);
    }
}

__global__ __launch_bounds__(256)
void k_apply(const float* __restrict__ x, const bf16_t* __restrict__ go,
             const float* __restrict__ mr, const float* __restrict__ gamma,
             const float* __restrict__ beta, float* __restrict__ out) {
    __shared__ float tr[32][65];
    int bid = blockIdx.x;
    const int tt = bid % 94; bid /= 94;
    const int nn = bid & 3;  bid >>= 2;
    const int g = bid & 7;
    const int b = bid >> 3;
    const int t0 = tt * 64, n0 = nn * 32;
    const int tid = threadIdx.x;
    const float mean = mr[(b * 8 + g) * 2], rstd = mr[(b * 8 + g) * 2 + 1];

    for (int idx = tid; idx < 2048; idx += 256) {
        int nl = idx & 31, tl = idx >> 5;
        int t = t0 + tl;
        float v = 0.f;
        if (t < Tt) v = (float)go[((size_t)((b * Tt + t) * Gg + g)) * Nn + n0 + nl];
        tr[nl][tl] = v;
    }
    __syncthreads();
    for (int idx = tid; idx < 2048; idx += 256) {
        int tl = idx & 63, nl = idx >> 6;
        int t = t0 + tl;
        if (t < Tt) {
            int n = n0 + nl;
            size_t a = ((size_t)((b * Gg + g) * Nn + n)) * Tt + t;
            out[a] = x[a] + gamma[n] * (tr[nl][tl] - mean) * rstd + beta[n];
        }
    }
}

extern "C" void kernel_launch(void* const* d_in, const int* in_sizes, int n_in,
                              void* d_out, int out_size, void* d_ws, size_t ws_size,
                              hipStream_t stream) {
    const float* x     = (const float*)d_in[0];
    const float* Wi    = (const float*)d_in[1];
    const float* bi    = (const float*)d_in[2];
    const float* ai    = (const float*)d_in[3];
    const float* Wm    = (const float*)d_in[4];
    const float* bm    = (const float*)d_in[5];
    const float* am    = (const float*)d_in[6];
    const float* Wo    = (const float*)d_in[7];
    const float* bo    = (const float*)d_in[8];
    const float* ao    = (const float*)d_in[9];
    const float* gamma = (const float*)d_in[10];
    const float* beta  = (const float*)d_in[11];
    float* out = (float*)d_out;
    char* ws = (char*)d_ws;

    if (ws_size < WS_NEED) return;  // ~50.2 MB scratch required

    bf16_t* WiB  = (bf16_t*)(ws + OFF_WI);
    bf16_t* WmB  = (bf16_t*)(ws + OFF_WM);
    bf16_t* WoB  = (bf16_t*)(ws + OFF_WO);
    float*  stat = (float*)(ws + OFF_ST);
    float*  mrs  = (float*)(ws + OFF_MRS);
    bf16_t* goB  = (bf16_t*)(ws + OFF_GO);

    k0_prep<<<dim3(512), dim3(256), 0, stream>>>(Wi, Wm, Wo, WiB, WmB, WoB, stat);
    k1_fused<<<dim3(Bq * (Tt / TB)), dim3(512), SMEM_BYTES, stream>>>(
        x, WiB, bi, ai, WmB, bm, am, WoB, bo, ao, goB, stat);
    k_final<<<dim3(1), dim3(64), 0, stream>>>(stat, mrs);
    k_apply<<<dim3(Bq * Gg * 4 * 94), dim3(256), 0, stream>>>(x, goB, mrs, gamma, beta, out);
}

// Round 2
// 254.846 us; speedup vs baseline: 1.2610x; 1.2610x over previous
//
#include <hip/hip_runtime.h>

typedef __bf16 bf16_t;
typedef __bf16 bf16x8 __attribute__((ext_vector_type(8)));
typedef float f32x4 __attribute__((ext_vector_type(4)));

static constexpr int Bq = 4, Gg = 8, Nn = 128, Tt = 6000, Hh = 384;
static constexpr int TB = 16;             // t-values per K1 block
static constexpr int MR = TB * Gg;        // 128 rows per block (row = tl*8 + g)
static constexpr int LDA = 136;           // As row stride (bf16)
static constexpr int LDG = 392;           // Gi row stride (196 words % 32 = 4 -> 2-way free)
static constexpr int LDSM = 392;          // Sm/Mm row stride
static constexpr int LDV = 132;           // Vv row stride (f32), 132 % 32 = 4

// workspace layout (bytes)
static constexpr size_t OFF_WI  = 0;                                  // 384x128 bf16
static constexpr size_t OFF_WM  = OFF_WI + (size_t)Hh * Nn * 2;       // 384x384 bf16
static constexpr size_t OFF_WO  = OFF_WM + (size_t)Hh * Hh * 2;       // 128x768 bf16
static constexpr size_t OFF_ST  = OFF_WO + (size_t)Nn * 2 * Hh * 2;   // 64x2 f32 (sum,sumsq)
static constexpr size_t OFF_MRS = OFF_ST + 64 * 2 * 4;                // 64x2 f32 (mean,rstd)
static constexpr size_t OFF_GO  = (size_t)1 << 20;                    // B*T*G*N bf16
static constexpr size_t WS_NEED = OFF_GO + (size_t)Bq * Tt * Gg * Nn * 2;

// k1 dynamic-LDS offsets (bytes). As [128][136] bf16 lives at 0 (dead after GEMM1).
static constexpr int SM_SM = 0;        // Sm [16][392] bf16 (reuses As region)
static constexpr int SM_MM = 12544;    // Mm [16][392] bf16
static constexpr int SM_VV = 25088;    // Vv [16][132] f32 (8448 B, ends 33536 <= 34816)
static constexpr int SM_GI = 34816;    // Gi [128][392] bf16
static constexpr int SM_STT = 135168;  // st [16] f32
static constexpr int SMEM_BYTES = 135232;

#define MFMA16(a, b, c) __builtin_amdgcn_mfma_f32_16x16x32_bf16((a), (b), (c), 0, 0, 0)

__global__ void k0_prep(const float* __restrict__ Wi, const float* __restrict__ Wm,
                        const float* __restrict__ Wo,
                        bf16_t* __restrict__ WiB, bf16_t* __restrict__ WmB,
                        bf16_t* __restrict__ WoB, float* __restrict__ stats) {
    int i = blockIdx.x * blockDim.x + threadIdx.x;
    const int n1 = Hh * Nn, n2 = Hh * Hh, n3 = Nn * 2 * Hh;
    for (int idx = i; idx < n1 + n2 + n3; idx += gridDim.x * blockDim.x) {
        if (idx < n1)            WiB[idx] = (bf16_t)Wi[idx];
        else if (idx < n1 + n2)  WmB[idx - n1] = (bf16_t)Wm[idx - n1];
        else                     WoB[idx - n1 - n2] = (bf16_t)Wo[idx - n1 - n2];
    }
    if (i < 128) stats[i] = 0.f;  // zero every launch: K1 atomically accumulates
}

// As column swizzle: element (row, c) stored at col c ^ swz(row) at 8-elem (16B) granularity.
// swz depends on (row>>3)&7 = tl&7 so the 16-way staging write conflict (lanes differing
// only in tl) spreads across 8 distinct 16B slots. Applied on BOTH write and read side.
__device__ __forceinline__ int as_col(int row, int c) {
    return ((((c >> 3) ^ ((row >> 3) & 7)) << 3) | (c & 7));
}

__global__ __launch_bounds__(512, 2)
void k1_fused(const float* __restrict__ x,
              const bf16_t* __restrict__ WiB, const float* __restrict__ bi, const float* __restrict__ aip,
              const bf16_t* __restrict__ WmB, const float* __restrict__ bm, const float* __restrict__ amp,
              const bf16_t* __restrict__ WoB, const float* __restrict__ bo, const float* __restrict__ aop,
              bf16_t* __restrict__ go, float* __restrict__ stats) {
    extern __shared__ char smem[];
    bf16_t* As = (bf16_t*)(smem);
    bf16_t* Sm = (bf16_t*)(smem + SM_SM);
    bf16_t* Mm = (bf16_t*)(smem + SM_MM);
    float*  Vv = (float*)(smem + SM_VV);
    bf16_t* Gi = (bf16_t*)(smem + SM_GI);
    float*  st = (float*)(smem + SM_STT);

    const int tid  = threadIdx.x;
    const int lane = tid & 63;
    const int w    = tid >> 6;       // wave 0..7
    const int l15  = lane & 15;
    const int l4   = lane >> 4;      // 0..3
    const int mh   = w >> 2;         // m-half (64 rows) for GEMM1/4
    const int ws4  = w & 3;          // col slice for GEMM1/4
    const int b    = blockIdx.x / (Tt / TB);
    const int t0   = (blockIdx.x % (Tt / TB)) * TB;

    if (tid < 16) st[tid] = 0.f;

    // ---- stage x[b, g, n, t0:t0+16] -> As[tl*8+g][swz(n)] (bf16)
    for (int idx = tid; idx < MR * Nn; idx += 512) {
        int tl = idx & 15;
        int gn = idx >> 4;
        int g = gn >> 7;
        int n = gn & 127;
        float v = x[((size_t)((b * Gg + g) * Nn + n)) * Tt + t0 + tl];
        int row = tl * Gg + g;
        As[row * LDA + as_col(row, n)] = (bf16_t)v;
    }
    __syncthreads();

    const float ai = aip[0], am = amp[0], ao = aop[0];

    // ---- GEMM1: Gi[128][384] = prelu(As @ WiB^T + bi), K=128
    // wave = 64-row half (mh) x 96-col slice (ws4): B-frag reused across 4 m-tiles.
    {
        const int cb = ws4 * 96;
        f32x4 acc[4][6];
        #pragma unroll
        for (int mt = 0; mt < 4; mt++)
            #pragma unroll
            for (int ni = 0; ni < 6; ni++) acc[mt][ni] = f32x4{0.f, 0.f, 0.f, 0.f};
        #pragma unroll
        for (int kk = 0; kk < 4; kk++) {
            const int k0 = kk * 32 + l4 * 8;
            bf16x8 a[4], bb[6];
            #pragma unroll
            for (int ni = 0; ni < 6; ni++)
                bb[ni] = *(const bf16x8*)&WiB[(cb + ni * 16 + l15) * Nn + k0];
            #pragma unroll
            for (int mt = 0; mt < 4; mt++) {
                int row = mh * 64 + mt * 16 + l15;
                a[mt] = *(const bf16x8*)&As[row * LDA + as_col(row, k0)];
            }
            #pragma unroll
            for (int mt = 0; mt < 4; mt++)
                #pragma unroll
                for (int ni = 0; ni < 6; ni++)
                    acc[mt][ni] = MFMA16(a[mt], bb[ni], acc[mt][ni]);
        }
        #pragma unroll
        for (int ni = 0; ni < 6; ni++) {
            int col = cb + ni * 16 + l15;
            float bv = bi[col];
            #pragma unroll
            for (int mt = 0; mt < 4; mt++) {
                #pragma unroll
                for (int j = 0; j < 4; j++) {
                    int row = mh * 64 + mt * 16 + l4 * 4 + j;
                    float v = acc[mt][ni][j] + bv;
                    v = v >= 0.f ? v : ai * v;
                    Gi[row * LDG + col] = (bf16_t)v;
                }
            }
        }
    }
    __syncthreads();

    // ---- group mean: Sm[tl][h0..h0+7] = (1/8) sum_g Gi[tl*8+g][h0..h0+7], vectorized
    for (int idx = tid; idx < TB * (Hh / 8); idx += 512) {
        int tl = idx / (Hh / 8);
        int h0 = (idx - tl * (Hh / 8)) * 8;
        float s[8];
        #pragma unroll
        for (int e = 0; e < 8; e++) s[e] = 0.f;
        #pragma unroll
        for (int g = 0; g < 8; g++) {
            bf16x8 vv = *(const bf16x8*)&Gi[(tl * 8 + g) * LDG + h0];
            #pragma unroll
            for (int e = 0; e < 8; e++) s[e] += (float)vv[e];
        }
        bf16x8 o;
        #pragma unroll
        for (int e = 0; e < 8; e++) o[e] = (bf16_t)(0.125f * s[e]);
        *(bf16x8*)&Sm[tl * LDSM + h0] = o;
    }
    __syncthreads();

    // ---- GEMM2: Mm[16][384] = prelu(Sm @ WmB^T + bm), K=384
    {
        const int cb2 = w * 48;
        f32x4 acc2[3];
        #pragma unroll
        for (int ni = 0; ni < 3; ni++) acc2[ni] = f32x4{0.f, 0.f, 0.f, 0.f};
        #pragma unroll
        for (int kk = 0; kk < 12; kk++) {
            const int k0 = kk * 32 + l4 * 8;
            bf16x8 a = *(const bf16x8*)&Sm[l15 * LDSM + k0];
            #pragma unroll
            for (int ni = 0; ni < 3; ni++) {
                bf16x8 bb = *(const bf16x8*)&WmB[(cb2 + ni * 16 + l15) * Hh + k0];
                acc2[ni] = MFMA16(a, bb, acc2[ni]);
            }
        }
        #pragma unroll
        for (int ni = 0; ni < 3; ni++) {
            int col = cb2 + ni * 16 + l15;
            float bv = bm[col];
            #pragma unroll
            for (int j = 0; j < 4; j++) {
                float v = acc2[ni][j] + bv;
                v = v >= 0.f ? v : am * v;
                Mm[(l4 * 4 + j) * LDSM + col] = (bf16_t)v;
            }
        }
    }
    __syncthreads();

    // ---- GEMM3: Vv[16][128] = Mm @ Wo2^T  (Wo2[n][o] = WoB[n*768 + 384 + o]), K=384
    {
        const int nblk = w * 16;
        f32x4 acc3 = f32x4{0.f, 0.f, 0.f, 0.f};
        #pragma unroll
        for (int kk = 0; kk < 12; kk++) {
            const int k0 = kk * 32 + l4 * 8;
            bf16x8 a = *(const bf16x8*)&Mm[l15 * LDSM + k0];
            bf16x8 bb = *(const bf16x8*)&WoB[(nblk + l15) * 768 + 384 + k0];
            acc3 = MFMA16(a, bb, acc3);
        }
        #pragma unroll
        for (int j = 0; j < 4; j++) Vv[(l4 * 4 + j) * LDV + nblk + l15] = acc3[j];
    }
    __syncthreads();

    // ---- GEMM4: go[128][128] = prelu(Gi @ Wo1^T + Vv + bo), K=384; plus LN partial stats
    // wave = 64-row half (mh) x 32-col slice (ws4): B-frag reused across 4 m-tiles.
    {
        const int cb4 = ws4 * 32;
        f32x4 acc4[4][2];
        #pragma unroll
        for (int mt = 0; mt < 4; mt++)
            #pragma unroll
            for (int ni = 0; ni < 2; ni++) acc4[mt][ni] = f32x4{0.f, 0.f, 0.f, 0.f};
        #pragma unroll
        for (int kk = 0; kk < 12; kk++) {
            const int k0 = kk * 32 + l4 * 8;
            bf16x8 b0 = *(const bf16x8*)&WoB[(cb4 + l15) * 768 + k0];
            bf16x8 b1 = *(const bf16x8*)&WoB[(cb4 + 16 + l15) * 768 + k0];
            bf16x8 a[4];
            #pragma unroll
            for (int mt = 0; mt < 4; mt++)
                a[mt] = *(const bf16x8*)&Gi[(mh * 64 + mt * 16 + l15) * LDG + k0];
            #pragma unroll
            for (int mt = 0; mt < 4; mt++) {
                acc4[mt][0] = MFMA16(a[mt], b0, acc4[mt][0]);
                acc4[mt][1] = MFMA16(a[mt], b1, acc4[mt][1]);
            }
        }
        // epilogue + per-(b,g) partial sums.  row = mh*64+mt*16+l4*4+j -> g = (l4*4+j)&7
        float gsum[4] = {0.f, 0.f, 0.f, 0.f};
        float gss[4]  = {0.f, 0.f, 0.f, 0.f};
        #pragma unroll
        for (int ni = 0; ni < 2; ni++) {
            int col = cb4 + ni * 16 + l15;
            float bv = bo[col];
            #pragma unroll
            for (int mt = 0; mt < 4; mt++) {
                #pragma unroll
                for (int j = 0; j < 4; j++) {
                    int row = mh * 64 + mt * 16 + l4 * 4 + j;
                    int tl = row >> 3;
                    int g = row & 7;
                    float v = acc4[mt][ni][j] + Vv[tl * LDV + col] + bv;
                    v = v >= 0.f ? v : ao * v;
                    go[((size_t)((b * Tt + t0 + tl) * Gg + g)) * Nn + col] = (bf16_t)v;
                    gsum[j] += v;
                    gss[j] += v * v;
                }
            }
        }
        #pragma unroll
        for (int j = 0; j < 4; j++) {
            float s = gsum[j], q = gss[j];
            #pragma unroll
            for (int off = 1; off < 16; off <<= 1) {
                s += __shfl_xor(s, off, 64);
                q += __shfl_xor(q, off, 64);
            }
            if (l15 == 0) {
                int g = (l4 * 4 + j) & 7;
                atomicAdd(&st[g * 2 + 0], s);
                atomicAdd(&st[g * 2 + 1], q);
            }
        }
    }
    __syncthreads();
    if (tid < 16) atomicAdd(&stats[b * 16 + tid], st[tid]);
}

__global__ void k_final(const float* __restrict__ stats, float* __restrict__ mr) {
    int i = threadIdx.x;
    if (i < 64) {
        const float cnt = (float)Nn * (float)Tt;  // 768000 per (b,g)
        float mean = stats[i * 2] / cnt;
        float var = stats[i * 2 + 1] / cnt - mean * mean;
        mr[i * 2] = mean;
        mr[i * 2 + 1] = rsqrtf(var + 1e-8f);
    }
}

__global__ __launch_bounds__(256)
void k_apply(const float* __restrict__ x, const bf16_t* __restrict__ go,
             const float* __restrict__ mr, const float* __restrict__ gamma,
             const float* __restrict__ beta, float* __restrict__ out) {
    __shared__ float tr[32][65];
    int bid = blockIdx.x;
    const int tt = bid % 94; bid /= 94;
    const int nn = bid & 3;  bid >>= 2;
    const int g = bid & 7;
    const int b = bid >> 3;
    const int t0 = tt * 64, n0 = nn * 32;
    const int tid = threadIdx.x;
    const float mean = mr[(b * 8 + g) * 2], rstd = mr[(b * 8 + g) * 2 + 1];

    for (int idx = tid; idx < 2048; idx += 256) {
        int nl = idx & 31, tl = idx >> 5;
        int t = t0 + tl;
        float v = 0.f;
        if (t < Tt) v = (float)go[((size_t)((b * Tt + t) * Gg + g)) * Nn + n0 + nl];
        tr[nl][tl] = v;
    }
    __syncthreads();
    for (int idx = tid; idx < 2048; idx += 256) {
        int tl = idx & 63, nl = idx >> 6;
        int t = t0 + tl;
        if (t < Tt) {
            int n = n0 + nl;
            size_t a = ((size_t)((b * Gg + g) * Nn + n)) * Tt + t;
            out[a] = x[a] + gamma[n] * (tr[nl][tl] - mean) * rstd + beta[n];
        }
    }
}

extern "C" void kernel_launch(void* const* d_in, const int* in_sizes, int n_in,
                              void* d_out, int out_size, void* d_ws, size_t ws_size,
                              hipStream_t stream) {
    const float* x     = (const float*)d_in[0];
    const float* Wi    = (const float*)d_in[1];
    const float* bi    = (const float*)d_in[2];
    const float* ai    = (const float*)d_in[3];
    const float* Wm    = (const float*)d_in[4];
    const float* bm    = (const float*)d_in[5];
    const float* am    = (const float*)d_in[6];
    const float* Wo    = (const float*)d_in[7];
    const float* bo    = (const float*)d_in[8];
    const float* ao    = (const float*)d_in[9];
    const float* gamma = (const float*)d_in[10];
    const float* beta  = (const float*)d_in[11];
    float* out = (float*)d_out;
    char* ws = (char*)d_ws;

    if (ws_size < WS_NEED) return;  // ~50.2 MB scratch required

    bf16_t* WiB  = (bf16_t*)(ws + OFF_WI);
    bf16_t* WmB  = (bf16_t*)(ws + OFF_WM);
    bf16_t* WoB  = (bf16_t*)(ws + OFF_WO);
    float*  stat = (float*)(ws + OFF_ST);
    float*  mrs  = (float*)(ws + OFF_MRS);
    bf16_t* goB  = (bf16_t*)(ws + OFF_GO);

    k0_prep<<<dim3(512), dim3(256), 0, stream>>>(Wi, Wm, Wo, WiB, WmB, WoB, stat);
    k1_fused<<<dim3(Bq * (Tt / TB)), dim3(512), SMEM_BYTES, stream>>>(
        x, WiB, bi, ai, WmB, bm, am, WoB, bo, ao, goB, stat);
    k_final<<<dim3(1), dim3(64), 0, stream>>>(stat, mrs);
    k_apply<<<dim3(Bq * Gg * 4 * 94), dim3(256), 0, stream>>>(x, goB, mrs, gamma, beta, out);
}